// Round 8
// baseline (123.369 us; speedup 1.0000x reference)
//
#include <hip/hip_runtime.h>
#include <hip/hip_bf16.h>
#include <stdint.h>

#define NG 16
#define NN 2048
#define DD 512
#define NROW (NG * NN)   // 32768
#define NTILE 16         // 2048 / 128
#define NPAIR 136        // NTILE*(NTILE+1)/2
#define NXCD 8

typedef __attribute__((ext_vector_type(8))) short short8;
typedef __attribute__((ext_vector_type(4))) float f32x4;

__device__ inline unsigned short f2bf(float f) {
  union { float f; unsigned int u; } c;
  c.f = f;
  unsigned int x = c.u;
  unsigned int r = (x + 0x7fffu + ((x >> 16) & 1u)) >> 16;  // RNE
  return (unsigned short)r;
}

__device__ inline void gload_lds16(const void* g, void* l) {
  __builtin_amdgcn_global_load_lds(
      (const __attribute__((address_space(1))) void*)g,
      (__attribute__((address_space(3))) void*)l, 16, 0, 0);
}

// ---------------- prep: sq[row] = ||h_row||^2 (f32), optional bf16 cast ----------------
template <bool WRITE_BF>
__global__ __launch_bounds__(256) void prep_kernel(const float* __restrict__ h,
                                                   unsigned short* __restrict__ hbf,
                                                   float* __restrict__ sq) {
  const int row = blockIdx.x * 4 + (threadIdx.x >> 6);
  const int lane = threadIdx.x & 63;
  const float* hr = h + (size_t)row * DD;
  float4 v0 = ((const float4*)hr)[lane * 2];
  float4 v1 = ((const float4*)hr)[lane * 2 + 1];
  float s = v0.x * v0.x + v0.y * v0.y + v0.z * v0.z + v0.w * v0.w +
            v1.x * v1.x + v1.y * v1.y + v1.z * v1.z + v1.w * v1.w;
  if (WRITE_BF) {
    union { unsigned short us[8]; uint4 u4; } pk;
    pk.us[0] = f2bf(v0.x); pk.us[1] = f2bf(v0.y);
    pk.us[2] = f2bf(v0.z); pk.us[3] = f2bf(v0.w);
    pk.us[4] = f2bf(v1.x); pk.us[5] = f2bf(v1.y);
    pk.us[6] = f2bf(v1.z); pk.us[7] = f2bf(v1.w);
    ((uint4*)(hbf + (size_t)row * DD))[lane] = pk.u4;
  }
#pragma unroll
  for (int off = 32; off > 0; off >>= 1) s += __shfl_xor(s, off, 64);
  if (lane == 0) sq[row] = s;
}

// ---------------- batched Gram GEMM + LDS-staged full-line epilogue ----------------
// Tri grid (bi<=bj), 128x128 tile, BK=64, 4 waves (2x2), 16x16x32 bf16 MFMA.
// K-loop: R2-proven global_load_lds staging into As/Bs (32 KB).
// Epilogue: reuse the same 32 KB as Cs; two 64-row halves; XOR-swizzled
// (slot ^ jl&31, 16-B slots) so both row-reads (mirror region) and
// column-gathers (transposed region) are bank-conflict-free. All global
// stores cover FULL 128-B lines. Stores are PLAIN (not nt): output lands in
// L2/L3 and writes back in HW-managed order (DRAM page locality) — the
// 256 MB Infinity Cache absorbs the 256 MB output.
template <bool USE_WS>
__global__ __launch_bounds__(256) void gram_kernel(const unsigned short* __restrict__ hbf,
                                                   const float* __restrict__ hf,
                                                   const float* __restrict__ sq,
                                                   float* __restrict__ out) {
  __shared__ __align__(16) char smem[32768];
  unsigned short* As = (unsigned short*)smem;            // 16 KB (K-loop)
  unsigned short* Bs = (unsigned short*)(smem + 16384);  // 16 KB (K-loop)
  // After the K-loop, all 32 KB become the C staging buffer.

  const int t = threadIdx.x;
  const int lane = t & 63, wid = t >> 6;
  const int wr = wid >> 1, wc = wid & 1;
  const int l16 = lane & 15, lhi = lane >> 4;

  const int bid = blockIdx.x;
  const int xcd = bid & (NXCD - 1);
  const int slot = bid >> 3;              // 0..271
  const int gh = (slot >= NPAIR) ? 1 : 0;
  const int g = xcd * 2 + gh;
  int p = slot - gh * NPAIR;              // 0..135
  int bi = 0, rowlen = NTILE;
  while (p >= rowlen) { p -= rowlen; ++bi; --rowlen; }
  const int bj = bi + p;

  const size_t rowA = (size_t)g * NN + bi * 128;
  const size_t rowB = (size_t)g * NN + bj * 128;

  f32x4 acc[4][4];
#pragma unroll
  for (int m = 0; m < 4; ++m)
#pragma unroll
    for (int n = 0; n < 4; ++n) acc[m][n] = (f32x4){0.f, 0.f, 0.f, 0.f};

  for (int kt = 0; kt < DD / 64; ++kt) {
    if (USE_WS) {
      const char* Ab = (const char*)(hbf + rowA * DD + kt * 64);
      const char* Bb = (const char*)(hbf + rowB * DD + kt * 64);
#pragma unroll
      for (int r = 0; r < 4; ++r) {
        const int off = r * 4096 + t * 16;   // byte offset in LDS tile
        const int rw = off >> 7;             // tile row (128B per row)
        const int cb = off & 127;            // byte within row
        gload_lds16(Ab + (size_t)rw * (DD * 2) + cb, (char*)As + r * 4096 + wid * 1024);
        gload_lds16(Bb + (size_t)rw * (DD * 2) + cb, (char*)Bs + r * 4096 + wid * 1024);
      }
    } else {
      const float* Af = hf + rowA * DD + kt * 64;
      const float* Bf = hf + rowB * DD + kt * 64;
#pragma unroll
      for (int r = 0; r < 4; ++r) {
        const int off = r * 4096 + t * 16;
        const int rw = off >> 7;
        const int c0 = (off & 127) >> 1;  // f32 column
        float4 a0 = *(const float4*)(Af + (size_t)rw * DD + c0);
        float4 a1 = *(const float4*)(Af + (size_t)rw * DD + c0 + 4);
        float4 b0 = *(const float4*)(Bf + (size_t)rw * DD + c0);
        float4 b1 = *(const float4*)(Bf + (size_t)rw * DD + c0 + 4);
        union { unsigned short us[8]; uint4 u4; } pa, pb;
        pa.us[0] = f2bf(a0.x); pa.us[1] = f2bf(a0.y);
        pa.us[2] = f2bf(a0.z); pa.us[3] = f2bf(a0.w);
        pa.us[4] = f2bf(a1.x); pa.us[5] = f2bf(a1.y);
        pa.us[6] = f2bf(a1.z); pa.us[7] = f2bf(a1.w);
        pb.us[0] = f2bf(b0.x); pb.us[1] = f2bf(b0.y);
        pb.us[2] = f2bf(b0.z); pb.us[3] = f2bf(b0.w);
        pb.us[4] = f2bf(b1.x); pb.us[5] = f2bf(b1.y);
        pb.us[6] = f2bf(b1.z); pb.us[7] = f2bf(b1.w);
        *(uint4*)((char*)As + off) = pa.u4;
        *(uint4*)((char*)Bs + off) = pb.u4;
      }
    }
    __syncthreads();
#pragma unroll
    for (int kk = 0; kk < 2; ++kk) {
      short8 af[4], bfr[4];
#pragma unroll
      for (int m = 0; m < 4; ++m)
        af[m] = *(const short8*)&As[(wr * 64 + m * 16 + l16) * 64 + kk * 32 + lhi * 8];
#pragma unroll
      for (int n = 0; n < 4; ++n)
        bfr[n] = *(const short8*)&Bs[(wc * 64 + n * 16 + l16) * 64 + kk * 32 + lhi * 8];
#pragma unroll
      for (int m = 0; m < 4; ++m)
#pragma unroll
        for (int n = 0; n < 4; ++n)
          acc[m][n] = __builtin_amdgcn_mfma_f32_16x16x32_bf16(af[m], bfr[n], acc[m][n], 0, 0, 0);
    }
    __syncthreads();  // also guards Cs reuse of As/Bs after the last iter
  }

  // ---------------- epilogue: val = sq_i + sq_j - 2*gram ----------------
  float sqr[4][4];
  float sqc[4];
#pragma unroll
  for (int m = 0; m < 4; ++m)
#pragma unroll
    for (int r = 0; r < 4; ++r)
      sqr[m][r] = sq[rowA + wr * 64 + m * 16 + lhi * 4 + r];
#pragma unroll
  for (int n = 0; n < 4; ++n) sqc[n] = sq[rowB + wc * 64 + n * 16 + l16];

  float* outg = out + (size_t)g * NN * NN;
  const bool offdiag = (bi != bj);

  // Cs logical layout per half: [jl 0..63][i' 0..127] f32, row = 512 B = 32
  // 16-B slots; physical slot index = slot ^ (jl & 31) (bijective per row).
#pragma unroll
  for (int hf = 0; hf < 2; ++hf) {
    if (wc == hf) {
      // This wave's acc covers j' = hf*64 + n*16+l16, i' = wr*64+m*16+lhi*4+r.
#pragma unroll
      for (int n = 0; n < 4; ++n)
#pragma unroll
        for (int m = 0; m < 4; ++m) {
          f32x4 v;
          v.x = sqr[m][0] + sqc[n] - 2.0f * acc[m][n][0];
          v.y = sqr[m][1] + sqc[n] - 2.0f * acc[m][n][1];
          v.z = sqr[m][2] + sqc[n] - 2.0f * acc[m][n][2];
          v.w = sqr[m][3] + sqc[n] - 2.0f * acc[m][n][3];
          const int jl = n * 16 + l16;                 // local row 0..63
          const int sw = (wr * 16 + m * 4 + lhi) ^ (jl & 31);  // swizzled slot
          *(f32x4*)(smem + jl * 512 + (sw << 4)) = v;
        }
    }
    __syncthreads();

    // Mirror region: out rows (bj*128 + hf*64 + jl), cols bi*128 .. +127.
    // 8 rows per iteration; each wave stores 2 rows x 512 B (4 full lines).
    {
      const int jrow0 = bj * 128 + hf * 64;
      const int s = t & 31;
#pragma unroll
      for (int k = 0; k < 8; ++k) {
        const int jl = k * 8 + (t >> 5);
        f32x4 v = *(const f32x4*)(smem + jl * 512 + ((s ^ (jl & 31)) << 4));
        *(f32x4*)&outg[(size_t)(jrow0 + jl) * NN + bi * 128 + s * 4] = v;
      }
    }
    // Transposed region (offdiag only): out rows bi*128 + i', cols
    // (bj*128 + hf*64) .. +63. Column-gather of 4 LDS rows per f32x4;
    // swizzle spreads the stride-512B rows across banks (<=2-way).
    if (offdiag) {
      const int jcol0 = bj * 128 + hf * 64;
      const int j0 = (t & 15) * 4;
#pragma unroll
      for (int k = 0; k < 8; ++k) {
        const int ip = k * 16 + (t >> 4);   // i' 0..127
        f32x4 v;
#pragma unroll
        for (int d = 0; d < 4; ++d) {
          const int jl = j0 + d;
          v[d] = *(const float*)(smem + jl * 512 + ((((ip >> 2) ^ (jl & 31)) << 4)) +
                                 (ip & 3) * 4);
        }
        *(f32x4*)&outg[(size_t)(bi * 128 + ip) * NN + jcol0 + j0] = v;
      }
    }
    if (hf == 0) __syncthreads();
  }
}

extern "C" void kernel_launch(void* const* d_in, const int* in_sizes, int n_in,
                              void* d_out, int out_size, void* d_ws, size_t ws_size,
                              hipStream_t stream) {
  const float* h = (const float*)d_in[0];
  float* out = (float*)d_out;

  float* sq = (float*)d_ws;                                   // 32768 f32 = 128 KB
  unsigned short* hbf = (unsigned short*)((char*)d_ws + NROW * 4);  // 32 MB bf16
  const size_t need_ws = (size_t)NROW * 4 + (size_t)NROW * DD * 2;
  const bool use_ws = ws_size >= need_ws;

  if (use_ws) {
    prep_kernel<true><<<NROW / 4, 256, 0, stream>>>(h, hbf, sq);
    gram_kernel<true><<<NG * NPAIR, 256, 0, stream>>>(hbf, nullptr, sq, out);
  } else {
    prep_kernel<false><<<NROW / 4, 256, 0, stream>>>(h, nullptr, sq);
    gram_kernel<false><<<NG * NPAIR, 256, 0, stream>>>(nullptr, h, sq, out);
  }
}

// Round 9
// 110.383 us; speedup vs baseline: 1.1177x; 1.1177x over previous
//
#include <hip/hip_runtime.h>
#include <hip/hip_bf16.h>
#include <stdint.h>

#define NG 16
#define NN 2048
#define DD 512
#define NROW (NG * NN)   // 32768
#define NTILE 16         // 2048 / 128
#define NPAIR 136        // NTILE*(NTILE+1)/2
#define NXCD 8

typedef __attribute__((ext_vector_type(8))) short short8;
typedef __attribute__((ext_vector_type(4))) float f32x4;

__device__ inline unsigned short f2bf(float f) {
  union { float f; unsigned int u; } c;
  c.f = f;
  unsigned int x = c.u;
  unsigned int r = (x + 0x7fffu + ((x >> 16) & 1u)) >> 16;  // RNE
  return (unsigned short)r;
}

__device__ inline void gload_lds16(const void* g, void* l) {
  __builtin_amdgcn_global_load_lds(
      (const __attribute__((address_space(1))) void*)g,
      (__attribute__((address_space(3))) void*)l, 16, 0, 0);
}

// Barrier that waits ONLY for LDS ops (lgkmcnt), letting global nt stores
// stay in flight. __syncthreads would emit s_waitcnt vmcnt(0) and drain the
// store pipe to DRAM at every epilogue phase — pure overhead since the
// stored data is never read by anyone.
__device__ inline void barrier_lds_only() {
  asm volatile("s_waitcnt lgkmcnt(0)" ::: "memory");
  __builtin_amdgcn_s_barrier();
}

// ---------------- prep: sq[row] = ||h_row||^2 (f32), optional bf16 cast ----------------
template <bool WRITE_BF>
__global__ __launch_bounds__(256) void prep_kernel(const float* __restrict__ h,
                                                   unsigned short* __restrict__ hbf,
                                                   float* __restrict__ sq) {
  const int row = blockIdx.x * 4 + (threadIdx.x >> 6);
  const int lane = threadIdx.x & 63;
  const float* hr = h + (size_t)row * DD;
  float4 v0 = ((const float4*)hr)[lane * 2];
  float4 v1 = ((const float4*)hr)[lane * 2 + 1];
  float s = v0.x * v0.x + v0.y * v0.y + v0.z * v0.z + v0.w * v0.w +
            v1.x * v1.x + v1.y * v1.y + v1.z * v1.z + v1.w * v1.w;
  if (WRITE_BF) {
    union { unsigned short us[8]; uint4 u4; } pk;
    pk.us[0] = f2bf(v0.x); pk.us[1] = f2bf(v0.y);
    pk.us[2] = f2bf(v0.z); pk.us[3] = f2bf(v0.w);
    pk.us[4] = f2bf(v1.x); pk.us[5] = f2bf(v1.y);
    pk.us[6] = f2bf(v1.z); pk.us[7] = f2bf(v1.w);
    ((uint4*)(hbf + (size_t)row * DD))[lane] = pk.u4;
  }
#pragma unroll
  for (int off = 32; off > 0; off >>= 1) s += __shfl_xor(s, off, 64);
  if (lane == 0) sq[row] = s;
}

// ---------------- batched Gram GEMM + LDS-staged full-line epilogue ----------------
// Tri grid (bi<=bj), 128x128 tile, BK=64, 4 waves (2x2), 16x16x32 bf16 MFMA.
// K-loop: R2-proven global_load_lds staging into As/Bs (32 KB).
// Epilogue: reuse the same 32 KB as Cs; two 64-row halves; XOR-swizzled
// (slot ^ jl&31, 16-B slots). All global stores are nt f32x4 covering FULL
// 128-B lines (R7: nt +13 us vs plain). Epilogue barriers are lgkm-only so
// nt stores never drain mid-epilogue.
template <bool USE_WS>
__global__ __launch_bounds__(256) void gram_kernel(const unsigned short* __restrict__ hbf,
                                                   const float* __restrict__ hf,
                                                   const float* __restrict__ sq,
                                                   float* __restrict__ out) {
  __shared__ __align__(16) char smem[32768];
  unsigned short* As = (unsigned short*)smem;            // 16 KB (K-loop)
  unsigned short* Bs = (unsigned short*)(smem + 16384);  // 16 KB (K-loop)
  // After the K-loop, all 32 KB become the C staging buffer.

  const int t = threadIdx.x;
  const int lane = t & 63, wid = t >> 6;
  const int wr = wid >> 1, wc = wid & 1;
  const int l16 = lane & 15, lhi = lane >> 4;

  const int bid = blockIdx.x;
  const int xcd = bid & (NXCD - 1);
  const int slot = bid >> 3;              // 0..271
  const int gh = (slot >= NPAIR) ? 1 : 0;
  const int g = xcd * 2 + gh;
  int p = slot - gh * NPAIR;              // 0..135
  int bi = 0, rowlen = NTILE;
  while (p >= rowlen) { p -= rowlen; ++bi; --rowlen; }
  const int bj = bi + p;

  const size_t rowA = (size_t)g * NN + bi * 128;
  const size_t rowB = (size_t)g * NN + bj * 128;

  f32x4 acc[4][4];
#pragma unroll
  for (int m = 0; m < 4; ++m)
#pragma unroll
    for (int n = 0; n < 4; ++n) acc[m][n] = (f32x4){0.f, 0.f, 0.f, 0.f};

  for (int kt = 0; kt < DD / 64; ++kt) {
    if (USE_WS) {
      const char* Ab = (const char*)(hbf + rowA * DD + kt * 64);
      const char* Bb = (const char*)(hbf + rowB * DD + kt * 64);
#pragma unroll
      for (int r = 0; r < 4; ++r) {
        const int off = r * 4096 + t * 16;   // byte offset in LDS tile
        const int rw = off >> 7;             // tile row (128B per row)
        const int cb = off & 127;            // byte within row
        gload_lds16(Ab + (size_t)rw * (DD * 2) + cb, (char*)As + r * 4096 + wid * 1024);
        gload_lds16(Bb + (size_t)rw * (DD * 2) + cb, (char*)Bs + r * 4096 + wid * 1024);
      }
    } else {
      const float* Af = hf + rowA * DD + kt * 64;
      const float* Bf = hf + rowB * DD + kt * 64;
#pragma unroll
      for (int r = 0; r < 4; ++r) {
        const int off = r * 4096 + t * 16;
        const int rw = off >> 7;
        const int c0 = (off & 127) >> 1;  // f32 column
        float4 a0 = *(const float4*)(Af + (size_t)rw * DD + c0);
        float4 a1 = *(const float4*)(Af + (size_t)rw * DD + c0 + 4);
        float4 b0 = *(const float4*)(Bf + (size_t)rw * DD + c0);
        float4 b1 = *(const float4*)(Bf + (size_t)rw * DD + c0 + 4);
        union { unsigned short us[8]; uint4 u4; } pa, pb;
        pa.us[0] = f2bf(a0.x); pa.us[1] = f2bf(a0.y);
        pa.us[2] = f2bf(a0.z); pa.us[3] = f2bf(a0.w);
        pa.us[4] = f2bf(a1.x); pa.us[5] = f2bf(a1.y);
        pa.us[6] = f2bf(a1.z); pa.us[7] = f2bf(a1.w);
        pb.us[0] = f2bf(b0.x); pb.us[1] = f2bf(b0.y);
        pb.us[2] = f2bf(b0.z); pb.us[3] = f2bf(b0.w);
        pb.us[4] = f2bf(b1.x); pb.us[5] = f2bf(b1.y);
        pb.us[6] = f2bf(b1.z); pb.us[7] = f2bf(b1.w);
        *(uint4*)((char*)As + off) = pa.u4;
        *(uint4*)((char*)Bs + off) = pb.u4;
      }
    }
    __syncthreads();
#pragma unroll
    for (int kk = 0; kk < 2; ++kk) {
      short8 af[4], bfr[4];
#pragma unroll
      for (int m = 0; m < 4; ++m)
        af[m] = *(const short8*)&As[(wr * 64 + m * 16 + l16) * 64 + kk * 32 + lhi * 8];
#pragma unroll
      for (int n = 0; n < 4; ++n)
        bfr[n] = *(const short8*)&Bs[(wc * 64 + n * 16 + l16) * 64 + kk * 32 + lhi * 8];
#pragma unroll
      for (int m = 0; m < 4; ++m)
#pragma unroll
        for (int n = 0; n < 4; ++n)
          acc[m][n] = __builtin_amdgcn_mfma_f32_16x16x32_bf16(af[m], bfr[n], acc[m][n], 0, 0, 0);
    }
    __syncthreads();  // also guards Cs reuse of As/Bs after the last iter
  }

  // ---------------- epilogue: val = sq_i + sq_j - 2*gram ----------------
  float sqr[4][4];
  float sqc[4];
#pragma unroll
  for (int m = 0; m < 4; ++m)
#pragma unroll
    for (int r = 0; r < 4; ++r)
      sqr[m][r] = sq[rowA + wr * 64 + m * 16 + lhi * 4 + r];
#pragma unroll
  for (int n = 0; n < 4; ++n) sqc[n] = sq[rowB + wc * 64 + n * 16 + l16];

  float* outg = out + (size_t)g * NN * NN;
  const bool offdiag = (bi != bj);

  // Cs logical layout per half: [jl 0..63][i' 0..127] f32, row = 512 B = 32
  // 16-B slots; physical slot index = slot ^ (jl & 31) (bijective per row).
#pragma unroll
  for (int hf = 0; hf < 2; ++hf) {
    if (wc == hf) {
      // This wave's acc covers j' = hf*64 + n*16+l16, i' = wr*64+m*16+lhi*4+r.
#pragma unroll
      for (int n = 0; n < 4; ++n)
#pragma unroll
        for (int m = 0; m < 4; ++m) {
          f32x4 v;
          v.x = sqr[m][0] + sqc[n] - 2.0f * acc[m][n][0];
          v.y = sqr[m][1] + sqc[n] - 2.0f * acc[m][n][1];
          v.z = sqr[m][2] + sqc[n] - 2.0f * acc[m][n][2];
          v.w = sqr[m][3] + sqc[n] - 2.0f * acc[m][n][3];
          const int jl = n * 16 + l16;                 // local row 0..63
          const int sw = (wr * 16 + m * 4 + lhi) ^ (jl & 31);  // swizzled slot
          *(f32x4*)(smem + jl * 512 + (sw << 4)) = v;
        }
    }
    barrier_lds_only();

    // Mirror region: out rows (bj*128 + hf*64 + jl), cols bi*128 .. +127.
    // Each wave stores 2 rows x 512 B (4 full lines) per iteration.
    {
      const int jrow0 = bj * 128 + hf * 64;
      const int s = t & 31;
#pragma unroll
      for (int k = 0; k < 8; ++k) {
        const int jl = k * 8 + (t >> 5);
        f32x4 v = *(const f32x4*)(smem + jl * 512 + ((s ^ (jl & 31)) << 4));
        __builtin_nontemporal_store(
            v, (f32x4*)&outg[(size_t)(jrow0 + jl) * NN + bi * 128 + s * 4]);
      }
    }
    // Transposed region (offdiag only): out rows bi*128 + i', cols
    // (bj*128 + hf*64) .. +63. Column-gather of 4 LDS rows per f32x4;
    // swizzle spreads the stride-512B rows across banks (<=2-way).
    if (offdiag) {
      const int jcol0 = bj * 128 + hf * 64;
      const int j0 = (t & 15) * 4;
#pragma unroll
      for (int k = 0; k < 8; ++k) {
        const int ip = k * 16 + (t >> 4);   // i' 0..127
        f32x4 v;
#pragma unroll
        for (int d = 0; d < 4; ++d) {
          const int jl = j0 + d;
          v[d] = *(const float*)(smem + jl * 512 + ((((ip >> 2) ^ (jl & 31)) << 4)) +
                                 (ip & 3) * 4);
        }
        __builtin_nontemporal_store(
            v, (f32x4*)&outg[(size_t)(bi * 128 + ip) * NN + jcol0 + j0]);
      }
    }
    if (hf == 0) barrier_lds_only();
  }
}

extern "C" void kernel_launch(void* const* d_in, const int* in_sizes, int n_in,
                              void* d_out, int out_size, void* d_ws, size_t ws_size,
                              hipStream_t stream) {
  const float* h = (const float*)d_in[0];
  float* out = (float*)d_out;

  float* sq = (float*)d_ws;                                   // 32768 f32 = 128 KB
  unsigned short* hbf = (unsigned short*)((char*)d_ws + NROW * 4);  // 32 MB bf16
  const size_t need_ws = (size_t)NROW * 4 + (size_t)NROW * DD * 2;
  const bool use_ws = ws_size >= need_ws;

  if (use_ws) {
    prep_kernel<true><<<NROW / 4, 256, 0, stream>>>(h, hbf, sq);
    gram_kernel<true><<<NG * NPAIR, 256, 0, stream>>>(hbf, nullptr, sq, out);
  } else {
    prep_kernel<false><<<NROW / 4, 256, 0, stream>>>(h, nullptr, sq);
    gram_kernel<false><<<NG * NPAIR, 256, 0, stream>>>(nullptr, h, sq, out);
  }
}

// Round 10
// 107.655 us; speedup vs baseline: 1.1460x; 1.0253x over previous
//
#include <hip/hip_runtime.h>
#include <hip/hip_bf16.h>
#include <stdint.h>

#define NG 16
#define NN 2048
#define DD 512
#define NROW (NG * NN)   // 32768
#define NTILE 16         // 2048 / 128
#define NPAIR 136        // NTILE*(NTILE+1)/2
#define NXCD 8

typedef __attribute__((ext_vector_type(8))) short short8;
typedef __attribute__((ext_vector_type(4))) float f32x4;

__device__ inline unsigned short f2bf(float f) {
  union { float f; unsigned int u; } c;
  c.f = f;
  unsigned int x = c.u;
  unsigned int r = (x + 0x7fffu + ((x >> 16) & 1u)) >> 16;  // RNE
  return (unsigned short)r;
}

__device__ inline void gload_lds16(const void* g, void* l) {
  __builtin_amdgcn_global_load_lds(
      (const __attribute__((address_space(1))) void*)g,
      (__attribute__((address_space(3))) void*)l, 16, 0, 0);
}

// Barrier that waits ONLY for LDS ops (lgkmcnt), letting global nt stores
// stay in flight.
__device__ inline void barrier_lds_only() {
  asm volatile("s_waitcnt lgkmcnt(0)" ::: "memory");
  __builtin_amdgcn_s_barrier();
}

// ---------------- prep: sq[row] = ||h_row||^2 (f32), optional bf16 cast ----------------
template <bool WRITE_BF>
__global__ __launch_bounds__(256) void prep_kernel(const float* __restrict__ h,
                                                   unsigned short* __restrict__ hbf,
                                                   float* __restrict__ sq) {
  const int row = blockIdx.x * 4 + (threadIdx.x >> 6);
  const int lane = threadIdx.x & 63;
  const float* hr = h + (size_t)row * DD;
  float4 v0 = ((const float4*)hr)[lane * 2];
  float4 v1 = ((const float4*)hr)[lane * 2 + 1];
  float s = v0.x * v0.x + v0.y * v0.y + v0.z * v0.z + v0.w * v0.w +
            v1.x * v1.x + v1.y * v1.y + v1.z * v1.z + v1.w * v1.w;
  if (WRITE_BF) {
    union { unsigned short us[8]; uint4 u4; } pk;
    pk.us[0] = f2bf(v0.x); pk.us[1] = f2bf(v0.y);
    pk.us[2] = f2bf(v0.z); pk.us[3] = f2bf(v0.w);
    pk.us[4] = f2bf(v1.x); pk.us[5] = f2bf(v1.y);
    pk.us[6] = f2bf(v1.z); pk.us[7] = f2bf(v1.w);
    ((uint4*)(hbf + (size_t)row * DD))[lane] = pk.u4;
  }
#pragma unroll
  for (int off = 32; off > 0; off >>= 1) s += __shfl_xor(s, off, 64);
  if (lane == 0) sq[row] = s;
}

// ---------------- batched Gram GEMM + LDS-staged full-line epilogue ----------------
// Tri grid (bi<=bj), 128x128 tile, BK=64, 4 waves (2x2), 16x16x32 bf16 MFMA.
// K-loop: global_load_lds staging into As/Bs (32 KB).
// Epilogue: reuse the 32 KB as Cs; XOR-swizzled; nt f32x4 full-line stores.
// NEW (R10): phase-staggered block start. All resident blocks on a CU
// otherwise convoy — K-phases (HBM idle) and store-phases (MFMA idle)
// alternate in lockstep chip-wide, so phase times ADD. A per-slot s_sleep
// stagger of ~1.2 us * ((slot>>5)&3) offsets resident blocks (slots ~32
// apart land on the same CU) so one block's stores overlap another's K-loop.
// Identical per-block work preserves the offset across all rounds.
template <bool USE_WS>
__global__ __launch_bounds__(256) void gram_kernel(const unsigned short* __restrict__ hbf,
                                                   const float* __restrict__ hf,
                                                   const float* __restrict__ sq,
                                                   float* __restrict__ out) {
  __shared__ __align__(16) char smem[32768];
  unsigned short* As = (unsigned short*)smem;            // 16 KB (K-loop)
  unsigned short* Bs = (unsigned short*)(smem + 16384);  // 16 KB (K-loop)

  const int t = threadIdx.x;
  const int lane = t & 63, wid = t >> 6;
  const int wr = wid >> 1, wc = wid & 1;
  const int l16 = lane & 15, lhi = lane >> 4;

  const int bid = blockIdx.x;
  const int xcd = bid & (NXCD - 1);
  const int slot = bid >> 3;              // 0..271
  const int gh = (slot >= NPAIR) ? 1 : 0;
  const int g = xcd * 2 + gh;
  int p = slot - gh * NPAIR;              // 0..135
  int bi = 0, rowlen = NTILE;
  while (p >= rowlen) { p -= rowlen; ++bi; --rowlen; }
  const int bj = bi + p;

  // Convoy-breaking stagger: 0 / ~1.2 / ~2.4 / ~3.6 us by slot group.
  {
    const int phase = (slot >> 5) & 3;
    for (int i = 0; i < phase * 3; ++i) __builtin_amdgcn_s_sleep(15);
  }

  const size_t rowA = (size_t)g * NN + bi * 128;
  const size_t rowB = (size_t)g * NN + bj * 128;

  f32x4 acc[4][4];
#pragma unroll
  for (int m = 0; m < 4; ++m)
#pragma unroll
    for (int n = 0; n < 4; ++n) acc[m][n] = (f32x4){0.f, 0.f, 0.f, 0.f};

  for (int kt = 0; kt < DD / 64; ++kt) {
    if (USE_WS) {
      const char* Ab = (const char*)(hbf + rowA * DD + kt * 64);
      const char* Bb = (const char*)(hbf + rowB * DD + kt * 64);
#pragma unroll
      for (int r = 0; r < 4; ++r) {
        const int off = r * 4096 + t * 16;   // byte offset in LDS tile
        const int rw = off >> 7;             // tile row (128B per row)
        const int cb = off & 127;            // byte within row
        gload_lds16(Ab + (size_t)rw * (DD * 2) + cb, (char*)As + r * 4096 + wid * 1024);
        gload_lds16(Bb + (size_t)rw * (DD * 2) + cb, (char*)Bs + r * 4096 + wid * 1024);
      }
    } else {
      const float* Af = hf + rowA * DD + kt * 64;
      const float* Bf = hf + rowB * DD + kt * 64;
#pragma unroll
      for (int r = 0; r < 4; ++r) {
        const int off = r * 4096 + t * 16;
        const int rw = off >> 7;
        const int c0 = (off & 127) >> 1;  // f32 column
        float4 a0 = *(const float4*)(Af + (size_t)rw * DD + c0);
        float4 a1 = *(const float4*)(Af + (size_t)rw * DD + c0 + 4);
        float4 b0 = *(const float4*)(Bf + (size_t)rw * DD + c0);
        float4 b1 = *(const float4*)(Bf + (size_t)rw * DD + c0 + 4);
        union { unsigned short us[8]; uint4 u4; } pa, pb;
        pa.us[0] = f2bf(a0.x); pa.us[1] = f2bf(a0.y);
        pa.us[2] = f2bf(a0.z); pa.us[3] = f2bf(a0.w);
        pa.us[4] = f2bf(a1.x); pa.us[5] = f2bf(a1.y);
        pa.us[6] = f2bf(a1.z); pa.us[7] = f2bf(a1.w);
        pb.us[0] = f2bf(b0.x); pb.us[1] = f2bf(b0.y);
        pb.us[2] = f2bf(b0.z); pb.us[3] = f2bf(b0.w);
        pb.us[4] = f2bf(b1.x); pb.us[5] = f2bf(b1.y);
        pb.us[6] = f2bf(b1.z); pb.us[7] = f2bf(b1.w);
        *(uint4*)((char*)As + off) = pa.u4;
        *(uint4*)((char*)Bs + off) = pb.u4;
      }
    }
    __syncthreads();
#pragma unroll
    for (int kk = 0; kk < 2; ++kk) {
      short8 af[4], bfr[4];
#pragma unroll
      for (int m = 0; m < 4; ++m)
        af[m] = *(const short8*)&As[(wr * 64 + m * 16 + l16) * 64 + kk * 32 + lhi * 8];
#pragma unroll
      for (int n = 0; n < 4; ++n)
        bfr[n] = *(const short8*)&Bs[(wc * 64 + n * 16 + l16) * 64 + kk * 32 + lhi * 8];
#pragma unroll
      for (int m = 0; m < 4; ++m)
#pragma unroll
        for (int n = 0; n < 4; ++n)
          acc[m][n] = __builtin_amdgcn_mfma_f32_16x16x32_bf16(af[m], bfr[n], acc[m][n], 0, 0, 0);
    }
    __syncthreads();  // also guards Cs reuse of As/Bs after the last iter
  }

  // ---------------- epilogue: val = sq_i + sq_j - 2*gram ----------------
  float sqr[4][4];
  float sqc[4];
#pragma unroll
  for (int m = 0; m < 4; ++m)
#pragma unroll
    for (int r = 0; r < 4; ++r)
      sqr[m][r] = sq[rowA + wr * 64 + m * 16 + lhi * 4 + r];
#pragma unroll
  for (int n = 0; n < 4; ++n) sqc[n] = sq[rowB + wc * 64 + n * 16 + l16];

  float* outg = out + (size_t)g * NN * NN;
  const bool offdiag = (bi != bj);

  // Cs logical layout per half: [jl 0..63][i' 0..127] f32, row = 512 B = 32
  // 16-B slots; physical slot index = slot ^ (jl & 31) (bijective per row).
#pragma unroll
  for (int hf = 0; hf < 2; ++hf) {
    if (wc == hf) {
#pragma unroll
      for (int n = 0; n < 4; ++n)
#pragma unroll
        for (int m = 0; m < 4; ++m) {
          f32x4 v;
          v.x = sqr[m][0] + sqc[n] - 2.0f * acc[m][n][0];
          v.y = sqr[m][1] + sqc[n] - 2.0f * acc[m][n][1];
          v.z = sqr[m][2] + sqc[n] - 2.0f * acc[m][n][2];
          v.w = sqr[m][3] + sqc[n] - 2.0f * acc[m][n][3];
          const int jl = n * 16 + l16;                 // local row 0..63
          const int sw = (wr * 16 + m * 4 + lhi) ^ (jl & 31);  // swizzled slot
          *(f32x4*)(smem + jl * 512 + (sw << 4)) = v;
        }
    }
    barrier_lds_only();

    // Mirror region: out rows (bj*128 + hf*64 + jl), cols bi*128 .. +127.
    {
      const int jrow0 = bj * 128 + hf * 64;
      const int s = t & 31;
#pragma unroll
      for (int k = 0; k < 8; ++k) {
        const int jl = k * 8 + (t >> 5);
        f32x4 v = *(const f32x4*)(smem + jl * 512 + ((s ^ (jl & 31)) << 4));
        __builtin_nontemporal_store(
            v, (f32x4*)&outg[(size_t)(jrow0 + jl) * NN + bi * 128 + s * 4]);
      }
    }
    // Transposed region (offdiag only).
    if (offdiag) {
      const int jcol0 = bj * 128 + hf * 64;
      const int j0 = (t & 15) * 4;
#pragma unroll
      for (int k = 0; k < 8; ++k) {
        const int ip = k * 16 + (t >> 4);   // i' 0..127
        f32x4 v;
#pragma unroll
        for (int d = 0; d < 4; ++d) {
          const int jl = j0 + d;
          v[d] = *(const float*)(smem + jl * 512 + ((((ip >> 2) ^ (jl & 31)) << 4)) +
                                 (ip & 3) * 4);
        }
        __builtin_nontemporal_store(
            v, (f32x4*)&outg[(size_t)(bi * 128 + ip) * NN + jcol0 + j0]);
      }
    }
    if (hf == 0) barrier_lds_only();
  }
}

extern "C" void kernel_launch(void* const* d_in, const int* in_sizes, int n_in,
                              void* d_out, int out_size, void* d_ws, size_t ws_size,
                              hipStream_t stream) {
  const float* h = (const float*)d_in[0];
  float* out = (float*)d_out;

  float* sq = (float*)d_ws;                                   // 32768 f32 = 128 KB
  unsigned short* hbf = (unsigned short*)((char*)d_ws + NROW * 4);  // 32 MB bf16
  const size_t need_ws = (size_t)NROW * 4 + (size_t)NROW * DD * 2;
  const bool use_ws = ws_size >= need_ws;

  if (use_ws) {
    prep_kernel<true><<<NROW / 4, 256, 0, stream>>>(h, hbf, sq);
    gram_kernel<true><<<NG * NPAIR, 256, 0, stream>>>(hbf, nullptr, sq, out);
  } else {
    prep_kernel<false><<<NROW / 4, 256, 0, stream>>>(h, nullptr, sq);
    gram_kernel<false><<<NG * NPAIR, 256, 0, stream>>>(nullptr, h, sq, out);
  }
}